// Round 1
// baseline (2682.739 us; speedup 1.0000x reference)
//
#include <hip/hip_runtime.h>
#include <hip/hip_bf16.h>

// One 64-lane wave per edge; lane d handles embedding dim d (D=64).
// For edge e with (r=rows[e], c=cols[e], v=vals[e]):
//   out_student[r][d] += v * problem_embeds[c][d]
//   out_problem[c][d] += v * student_embeds[r][d]
// Both the gathers and the atomic scatters are coalesced 256B/wave.
__global__ void spmm_scatter_kernel(const int* __restrict__ rows,
                                    const int* __restrict__ cols,
                                    const float* __restrict__ vals,
                                    const float* __restrict__ s_emb,   // [NS,64]
                                    const float* __restrict__ p_emb,   // [NP,64]
                                    float* __restrict__ out_s,         // [NS,64]
                                    float* __restrict__ out_p,         // [NP,64]
                                    int nnz)
{
    long long t = (long long)blockIdx.x * blockDim.x + threadIdx.x;
    int e = (int)(t >> 6);
    int d = (int)(t & 63);
    if (e >= nnz) return;

    int   r = rows[e];      // wave-uniform (all 64 lanes same address -> broadcast)
    int   c = cols[e];
    float v = vals[e];

    float pv = p_emb[(size_t)c * 64 + d];
    float sv = s_emb[(size_t)r * 64 + d];

    atomicAdd(&out_s[(size_t)r * 64 + d], v * pv);
    atomicAdd(&out_p[(size_t)c * 64 + d], v * sv);
}

extern "C" void kernel_launch(void* const* d_in, const int* in_sizes, int n_in,
                              void* d_out, int out_size, void* d_ws, size_t ws_size,
                              hipStream_t stream)
{
    const float* s_emb   = (const float*)d_in[0];   // [NS,64]
    const float* p_emb   = (const float*)d_in[1];   // [NP,64]
    const int*   a_rows  = (const int*)d_in[2];
    const int*   a_cols  = (const int*)d_in[3];
    const float* a_vals  = (const float*)d_in[4];
    const int*   ia_rows = (const int*)d_in[5];
    const int*   ia_cols = (const int*)d_in[6];
    const float* ia_vals = (const float*)d_in[7];

    const int NS  = in_sizes[0] / 64;   // 50000
    const int NP  = in_sizes[1] / 64;   // 10000
    const int nnz = in_sizes[2];        // 3200000

    float* out = (float*)d_out;
    // Return order: (student_c, student_ic, problem_c, problem_ic)
    float* out_sc  = out;
    float* out_sic = out_sc  + (size_t)NS * 64;
    float* out_pc  = out_sic + (size_t)NS * 64;
    float* out_pic = out_pc  + (size_t)NP * 64;

    // Outputs are poisoned with 0xAA before every timed launch — zero them.
    hipMemsetAsync(d_out, 0, (size_t)out_size * sizeof(float), stream);

    const int block = 256;                      // 4 edges per block
    const long long total = (long long)nnz * 64;
    const int grid = (int)((total + block - 1) / block);

    // a-matrix: student_c and problem_c
    spmm_scatter_kernel<<<grid, block, 0, stream>>>(
        a_rows, a_cols, a_vals, s_emb, p_emb, out_sc, out_pc, nnz);
    // ia-matrix: student_ic and problem_ic
    spmm_scatter_kernel<<<grid, block, 0, stream>>>(
        ia_rows, ia_cols, ia_vals, s_emb, p_emb, out_sic, out_pic, nnz);
}

// Round 2
// 2355.440 us; speedup vs baseline: 1.1390x; 1.1390x over previous
//
#include <hip/hip_runtime.h>
#include <hip/hip_bf16.h>

#define SCAN_B 256

// ---------------- counting-sort phase ----------------

__global__ void hist_kernel(const int* __restrict__ key, int* __restrict__ cnt, int nnz) {
    int i = blockIdx.x * blockDim.x + threadIdx.x;
    if (i < nnz) atomicAdd(&cnt[key[i]], 1);
}

// per-block exclusive scan + block totals
__global__ void scan_p1(const int* __restrict__ in, int* __restrict__ excl,
                        int* __restrict__ bsum, int n) {
    __shared__ int tmp[SCAN_B];
    int i = blockIdx.x * SCAN_B + threadIdx.x;
    int v = (i < n) ? in[i] : 0;
    tmp[threadIdx.x] = v;
    __syncthreads();
    for (int off = 1; off < SCAN_B; off <<= 1) {
        int t = (threadIdx.x >= off) ? tmp[threadIdx.x - off] : 0;
        __syncthreads();
        tmp[threadIdx.x] += t;
        __syncthreads();
    }
    if (i < n) excl[i] = tmp[threadIdx.x] - v;
    if (threadIdx.x == SCAN_B - 1) bsum[blockIdx.x] = tmp[threadIdx.x];
}

// single-block exclusive scan of block totals (nb <= 256 guaranteed: 50000/256=196)
__global__ void scan_p2(int* __restrict__ bsum, int nb) {
    __shared__ int tmp[SCAN_B];
    int v = (threadIdx.x < nb) ? bsum[threadIdx.x] : 0;
    tmp[threadIdx.x] = v;
    __syncthreads();
    for (int off = 1; off < SCAN_B; off <<= 1) {
        int t = (threadIdx.x >= off) ? tmp[threadIdx.x - off] : 0;
        __syncthreads();
        tmp[threadIdx.x] += t;
        __syncthreads();
    }
    if (threadIdx.x < nb) bsum[threadIdx.x] = tmp[threadIdx.x] - v;
}

__global__ void scan_p3(const int* __restrict__ excl, const int* __restrict__ bsum,
                        int* __restrict__ offs, int* __restrict__ cursor, int n, int nnz) {
    int i = blockIdx.x * SCAN_B + threadIdx.x;
    if (i < n) {
        int o = excl[i] + bsum[blockIdx.x];
        offs[i] = o;
        cursor[i] = o;
    }
    if (i == 0) offs[n] = nnz;
}

// permute edges into destination-bucket order; pack (other_idx, val) as uint2
__global__ void scatter_kernel(const int* __restrict__ key, const int* __restrict__ other,
                               const float* __restrict__ vals, int* __restrict__ cursor,
                               uint2* __restrict__ edges, int nnz) {
    int i = blockIdx.x * blockDim.x + threadIdx.x;
    if (i < nnz) {
        int k = key[i];
        int slot = atomicAdd(&cursor[k], 1);
        edges[slot] = make_uint2((unsigned)other[i], __float_as_uint(vals[i]));
    }
}

// ---------------- gather SpMM: one 64-lane wave per output row ----------------
// Chunked: lanes cooperatively load 64 edges (coalesced 512B), broadcast via shfl,
// each lane accumulates its own dim d. Output written exactly once, no atomics.
__global__ void gather_kernel(const int* __restrict__ offs, const uint2* __restrict__ edges,
                              const float* __restrict__ x, float* __restrict__ out, int nrows) {
    int r = blockIdx.x * (blockDim.x >> 6) + (threadIdx.x >> 6);
    int lane = threadIdx.x & 63;
    if (r >= nrows) return;
    int beg = offs[r], end = offs[r + 1];
    float acc = 0.f;
    for (int base = beg; base < end; base += 64) {
        int n = end - base;
        if (n > 64) n = 64;
        uint2 ed = make_uint2(0u, 0u);
        if (lane < n) ed = edges[base + lane];
        for (int j = 0; j < n; ++j) {
            int   c = __shfl((int)ed.x, j);
            float v = __uint_as_float(__shfl((int)ed.y, j));
            acc += v * x[(size_t)c * 64 + lane];
        }
    }
    out[(size_t)r * 64 + lane] = acc;
}

// ---------------- fallback (round-1 atomic path, used only if ws too small) ----------------
__global__ void spmm_scatter_kernel(const int* __restrict__ rows, const int* __restrict__ cols,
                                    const float* __restrict__ vals,
                                    const float* __restrict__ s_emb, const float* __restrict__ p_emb,
                                    float* __restrict__ out_s, float* __restrict__ out_p, int nnz) {
    long long t = (long long)blockIdx.x * blockDim.x + threadIdx.x;
    int e = (int)(t >> 6);
    int d = (int)(t & 63);
    if (e >= nnz) return;
    int r = rows[e];
    int c = cols[e];
    float v = vals[e];
    atomicAdd(&out_s[(size_t)r * 64 + d], v * p_emb[(size_t)c * 64 + d]);
    atomicAdd(&out_p[(size_t)c * 64 + d], v * s_emb[(size_t)r * 64 + d]);
}

// ---------------- host ----------------

static void run_dir(const int* key, const int* other, const float* vals,
                    const float* x, float* out, int nrows, int nnz,
                    uint2* edges, int* cnt, int* excl, int* offs, int* cursor, int* bsum,
                    hipStream_t stream) {
    hipMemsetAsync(cnt, 0, (size_t)nrows * sizeof(int), stream);
    int gb = (nnz + 255) / 256;
    hist_kernel<<<gb, 256, 0, stream>>>(key, cnt, nnz);
    int nb = (nrows + SCAN_B - 1) / SCAN_B;
    scan_p1<<<nb, SCAN_B, 0, stream>>>(cnt, excl, bsum, nrows);
    scan_p2<<<1, SCAN_B, 0, stream>>>(bsum, nb);
    scan_p3<<<nb, SCAN_B, 0, stream>>>(excl, bsum, offs, cursor, nrows, nnz);
    scatter_kernel<<<gb, 256, 0, stream>>>(key, other, vals, cursor, edges, nnz);
    int gg = (nrows + 3) / 4;  // 4 waves (rows) per 256-thread block
    gather_kernel<<<gg, 256, 0, stream>>>(offs, edges, x, out, nrows);
}

extern "C" void kernel_launch(void* const* d_in, const int* in_sizes, int n_in,
                              void* d_out, int out_size, void* d_ws, size_t ws_size,
                              hipStream_t stream) {
    const float* s_emb   = (const float*)d_in[0];
    const float* p_emb   = (const float*)d_in[1];
    const int*   a_rows  = (const int*)d_in[2];
    const int*   a_cols  = (const int*)d_in[3];
    const float* a_vals  = (const float*)d_in[4];
    const int*   ia_rows = (const int*)d_in[5];
    const int*   ia_cols = (const int*)d_in[6];
    const float* ia_vals = (const float*)d_in[7];

    const int NS  = in_sizes[0] / 64;   // 50000
    const int NP  = in_sizes[1] / 64;   // 10000
    const int nnz = in_sizes[2];        // 3200000

    float* out = (float*)d_out;
    float* out_sc  = out;
    float* out_sic = out_sc  + (size_t)NS * 64;
    float* out_pc  = out_sic + (size_t)NS * 64;
    float* out_pic = out_pc  + (size_t)NP * 64;

    const int Nmax = (NS > NP) ? NS : NP;
    const size_t edges_bytes = (size_t)nnz * sizeof(uint2);
    const size_t iarr        = (size_t)(Nmax + 1) * sizeof(int);
    const size_t need        = edges_bytes + 4 * iarr + SCAN_B * sizeof(int) + 64;

    if (ws_size < need) {
        // fallback: atomic scatter (round-1 path)
        hipMemsetAsync(d_out, 0, (size_t)out_size * sizeof(float), stream);
        const long long total = (long long)nnz * 64;
        const int grid = (int)((total + 255) / 256);
        spmm_scatter_kernel<<<grid, 256, 0, stream>>>(a_rows, a_cols, a_vals, s_emb, p_emb,
                                                      out_sc, out_pc, nnz);
        spmm_scatter_kernel<<<grid, 256, 0, stream>>>(ia_rows, ia_cols, ia_vals, s_emb, p_emb,
                                                      out_sic, out_pic, nnz);
        return;
    }

    char* w = (char*)d_ws;
    uint2* edges  = (uint2*)w;                w += edges_bytes;
    int*   cnt    = (int*)w;                  w += iarr;
    int*   excl   = (int*)w;                  w += iarr;
    int*   offs   = (int*)w;                  w += iarr;
    int*   cursor = (int*)w;                  w += iarr;
    int*   bsum   = (int*)w;

    // 4 directions, sequential reuse of sort buffers:
    // a by row   -> out_sc  (x = p_emb, nrows = NS)
    run_dir(a_rows, a_cols, a_vals, p_emb, out_sc, NS, nnz, edges, cnt, excl, offs, cursor, bsum, stream);
    // a by col   -> out_pc  (x = s_emb, nrows = NP)
    run_dir(a_cols, a_rows, a_vals, s_emb, out_pc, NP, nnz, edges, cnt, excl, offs, cursor, bsum, stream);
    // ia by row  -> out_sic (x = p_emb, nrows = NS)
    run_dir(ia_rows, ia_cols, ia_vals, p_emb, out_sic, NS, nnz, edges, cnt, excl, offs, cursor, bsum, stream);
    // ia by col  -> out_pic (x = s_emb, nrows = NP)
    run_dir(ia_cols, ia_rows, ia_vals, s_emb, out_pic, NP, nnz, edges, cnt, excl, offs, cursor, bsum, stream);
}